// Round 7
// baseline (323.496 us; speedup 1.0000x reference)
//
#include <hip/hip_runtime.h>

// 3-layer GraphSAGE, N=100000, F=H=128, E=1.6M.
// bf16 features, weights hi/lo split -> 2-term MFMA, Z=[agg|root] layout.
// One-pass slab CSR build; fused prep kernel; zero-row padded gather.
// THIS VERSION: k_aggZ = exact round-0 body (verified 59us, ~3.3 TB/s fill
// wall, FETCH at per-XCD dedupe floor -> structural). k_sage2 re-tiled:
// 32 rows/wave (s=2) instead of 64 -> grid 391->782 blocks, 12.2 waves/CU
// (3/SIMD, pinned by launch_bounds(256,3), ~145 VGPR fits 170 budget).
// Fixes the GEMM's wave starvation (was 1.5 waves/SIMD, ~50us each,
// latency-bound on L2 weight reads with no TLP to hide them).

#define NN 100000
#define NB 391          // ceil(100000/256) buckets of 256 dst nodes
#define SLAB 5120       // slab capacity per bucket (mean 4096, sigma 64)

typedef short bf16x8 __attribute__((ext_vector_type(8)));
typedef float f32x4 __attribute__((ext_vector_type(4)));

static __device__ __forceinline__ float uaf(unsigned u) { return __uint_as_float(u); }
static __device__ __forceinline__ unsigned short f2bf(float f) {
  unsigned u = __float_as_uint(f);
  u += 0x7fffu + ((u >> 16) & 1u);
  return (unsigned short)(u >> 16);
}

// ---------------- fused prep: scatter | cvt_x | cvt_w | zero rows ----------------
__global__ __launch_bounds__(256) void k_prep(
    const int* __restrict__ src, const int* __restrict__ dst, int E, int SB,
    int* __restrict__ cursor, unsigned* __restrict__ pairs,
    const float* __restrict__ x, unsigned short* __restrict__ Z1,
    unsigned short* __restrict__ Z2,
    const float* __restrict__ W1l, const float* __restrict__ W1r,
    const float* __restrict__ W2l, const float* __restrict__ W2r,
    unsigned short* __restrict__ wt1h, unsigned short* __restrict__ wt1l,
    unsigned short* __restrict__ wt2h, unsigned short* __restrict__ wt2l) {
  __shared__ int h[NB];
  __shared__ int rb[NB];
  const int b = blockIdx.x;
  const int tid = threadIdx.x;
  const int XB = NN * 16 / 256;  // 6250 cvt_x blocks

  if (b < SB) {
    // ---- edge scatter into bucket slabs ----
    for (int i = tid; i < NB; i += 256) h[i] = 0;
    __syncthreads();
    int s[8], d[8];
    const int base = b * 2048 + tid * 8;
    #pragma unroll
    for (int i = 0; i < 8; i++) {
      int g = base + i;
      bool ok = g < E;
      s[i] = ok ? src[g] : 0;
      d[i] = ok ? dst[g] : -1;
      if (ok) atomicAdd(&h[d[i] >> 8], 1);
    }
    __syncthreads();
    for (int i = tid; i < NB; i += 256) {
      rb[i] = h[i] ? atomicAdd(&cursor[i], h[i]) : 0;
      h[i] = 0;
    }
    __syncthreads();
    #pragma unroll
    for (int i = 0; i < 8; i++) {
      if (d[i] >= 0) {
        int bk = d[i] >> 8;
        int off = rb[bk] + atomicAdd(&h[bk], 1);
        if (off < SLAB)
          pairs[(size_t)bk * SLAB + off] =
              ((unsigned)(d[i] & 255) << 17) | (unsigned)s[i];
      }
    }
  } else if (b < SB + XB) {
    // ---- x fp32 -> bf16 into Z1 root half ----
    int t = (b - SB) * 256 + tid;      // t < N*16
    int node = t >> 4, c = t & 15;
    const float4* xp = (const float4*)(x + (size_t)node * 128 + c * 8);
    float4 a = xp[0], bb = xp[1];
    float v[8] = {a.x, a.y, a.z, a.w, bb.x, bb.y, bb.z, bb.w};
    unsigned hh[8];
    #pragma unroll
    for (int i = 0; i < 8; i++) hh[i] = f2bf(v[i]);
    uint4 p;
    p.x = hh[0] | (hh[1] << 16); p.y = hh[2] | (hh[3] << 16);
    p.z = hh[4] | (hh[5] << 16); p.w = hh[6] | (hh[7] << 16);
    *(uint4*)(Z1 + (size_t)node * 256 + 128 + c * 8) = p;
  } else if (b < SB + XB + 64) {
    // ---- weight transpose + hi/lo split ----
    #pragma unroll
    for (int it = 0; it < 4; it++) {
      int t = (b - SB - XB) * 1024 + it * 256 + tid;  // t < 65536
      int layer = t >> 15;
      int rem = t & 32767;
      int k = rem >> 7;
      int nn = rem & 127;
      const float* Wl = layer ? W2l : W1l;
      const float* Wr = layer ? W2r : W1r;
      float v = (k < 128) ? Wl[k * 128 + nn] : Wr[(k - 128) * 128 + nn];
      unsigned short hv = f2bf(v);
      unsigned short lv = f2bf(v - uaf(((unsigned)hv) << 16));
      (layer ? wt2h : wt1h)[nn * 256 + k] = hv;
      (layer ? wt2l : wt1l)[nn * 256 + k] = lv;
    }
  } else {
    // ---- zero row N of Z1/Z2 (padding row for gather) ----
    unsigned* z1r = (unsigned*)(Z1 + (size_t)NN * 256);
    unsigned* z2r = (unsigned*)(Z2 + (size_t)NN * 256);
    if (tid < 128) z1r[tid] = 0;
    else z2r[tid - 128] = 0;
  }
}

// ---------------- per-bucket CSR build ----------------
__global__ __launch_bounds__(256) void k_build(const unsigned* __restrict__ pairs,
                                               const int* __restrict__ cursor,
                                               int* __restrict__ beg, int* __restrict__ deg,
                                               int* __restrict__ csr, int N) {
  __shared__ int cnt[256];
  __shared__ int sd[256];
  __shared__ int cur[256];
  const int b = blockIdx.x;
  const int tid = threadIdx.x;
  const size_t p0 = (size_t)b * SLAB;
  int count = cursor[b];
  if (count > SLAB) count = SLAB;
  cnt[tid] = 0;
  cur[tid] = 0;
  __syncthreads();
  for (int i = tid; i < count; i += 256) atomicAdd(&cnt[pairs[p0 + i] >> 17], 1);
  __syncthreads();
  int v = cnt[tid];
  sd[tid] = v;
  __syncthreads();
  #pragma unroll
  for (int off = 1; off < 256; off <<= 1) {
    int u = (tid >= off) ? sd[tid - off] : 0;
    __syncthreads();
    sd[tid] += u;
    __syncthreads();
  }
  const int node = b * 256 + tid;
  if (node < N) {
    beg[node] = (int)p0 + (sd[tid] - v);
    deg[node] = v;
  }
  __syncthreads();
  for (int i = tid; i < count; i += 256) {
    unsigned pv = pairs[p0 + i];
    int dl = pv >> 17;
    int pos = (sd[dl] - cnt[dl]) + atomicAdd(&cur[dl], 1);
    csr[p0 + pos] = pv & 0x1ffff;
  }
}

// accumulate 8 bf16 (packed in uint4) into float acc[8] -- bit-exact unpack order
#define ACC8(v)                                   \
  acc[0] += uaf((v).x << 16);                     \
  acc[1] += uaf((v).x & 0xffff0000u);             \
  acc[2] += uaf((v).y << 16);                     \
  acc[3] += uaf((v).y & 0xffff0000u);             \
  acc[4] += uaf((v).z << 16);                     \
  acc[5] += uaf((v).z & 0xffff0000u);             \
  acc[6] += uaf((v).w << 16);                     \
  acc[7] += uaf((v).w & 0xffff0000u);

// ---------------- mean aggregation over Z root halves (round-0 verified) ----------------
__global__ __launch_bounds__(256) void k_aggZ(unsigned short* __restrict__ Z,
                                              const int* __restrict__ begA,
                                              const int* __restrict__ degA,
                                              const int* __restrict__ csr, int n) {
  const int wid = (blockIdx.x * blockDim.x + threadIdx.x) >> 6;
  const int lane = threadIdx.x & 63;
  if (wid >= n) return;
  const int beg = begA[wid];
  const int d = degA[wid];
  const int g = lane >> 4, c = lane & 15;
  float acc[8] = {0.f, 0.f, 0.f, 0.f, 0.f, 0.f, 0.f, 0.f};

  for (int base = 0; base < d; base += 64) {
    int m = d - base;
    if (m > 64) m = 64;
    int idx = csr[beg + base + (lane < m ? lane : 0)];
    for (int k = 0; k < m; k += 32) {
      uint4 vA[4], vB[4];
      const bool hasB = (k + 16) < m;
      #pragma unroll
      for (int u = 0; u < 4; u++) {
        int kk = k + u * 4 + g;
        int j = __shfl(idx, kk & 63);
        j = (kk < m) ? j : NN;  // zero row
        vA[u] = *(const uint4*)(Z + (size_t)j * 256 + 128 + c * 8);
      }
      if (hasB) {
        #pragma unroll
        for (int u = 0; u < 4; u++) {
          int kk = k + 16 + u * 4 + g;
          int j = __shfl(idx, kk & 63);
          j = (kk < m) ? j : NN;
          vB[u] = *(const uint4*)(Z + (size_t)j * 256 + 128 + c * 8);
        }
      }
      #pragma unroll
      for (int u = 0; u < 4; u++) { ACC8(vA[u]); }
      if (hasB) {
        #pragma unroll
        for (int u = 0; u < 4; u++) { ACC8(vB[u]); }
      }
    }
  }
  #pragma unroll
  for (int j = 0; j < 8; j++) {
    acc[j] += __shfl_xor(acc[j], 16);
    acc[j] += __shfl_xor(acc[j], 32);
  }
  const float inv = d > 0 ? 1.0f / (float)d : 0.f;
  if (g == 0) {
    unsigned h[8];
    #pragma unroll
    for (int j = 0; j < 8; j++) h[j] = f2bf(acc[j] * inv);
    uint4 p;
    p.x = h[0] | (h[1] << 16); p.y = h[2] | (h[3] << 16);
    p.z = h[4] | (h[5] << 16); p.w = h[6] | (h[7] << 16);
    *(uint4*)(Z + (size_t)wid * 256 + c * 8) = p;
  }
}

// ---------------- streaming MFMA SAGE layer (32 rows/wave, 782 blocks) ----------------
// MODE 0: out = relu(Z@W + b) bf16 -> outB[node*256 + 128 + f] (Z2 root half)
// MODE 1: h = relu(Z@W + b) fp32 regs; s2 = h.w3l, r2 = h.w3r (fused layer 3)
// 32 rows per wave (s=0..1): ~145 VGPR -> 3 waves/SIMD; grid 782 blocks gives
// 12.2 waves/CU so the L2 weight-read latency is TLP-hidden (was 1.5/SIMD).
template <int MODE>
__global__ __launch_bounds__(256, 3) void k_sage2(
    const unsigned short* __restrict__ Z, const unsigned short* __restrict__ WTh,
    const unsigned short* __restrict__ WTl, const float* __restrict__ bias,
    unsigned short* __restrict__ outB,
    const float* __restrict__ w3l, const float* __restrict__ w3r,
    float* __restrict__ s2, float* __restrict__ r2, int n) {
  const int tid = threadIdx.x;
  const int lane = tid & 63;
  const int w = tid >> 6;
  const int ln = lane & 15;
  const int r16 = lane >> 4;
  const int m0 = blockIdx.x * 128 + w * 32;

  f32x4 acc[2][8];
  #pragma unroll
  for (int s = 0; s < 2; s++)
    #pragma unroll
    for (int cc = 0; cc < 8; cc++) {
      acc[s][cc][0] = 0.f; acc[s][cc][1] = 0.f;
      acc[s][cc][2] = 0.f; acc[s][cc][3] = 0.f;
    }
  float bv[8];
  #pragma unroll
  for (int cc = 0; cc < 8; cc++) bv[cc] = bias[cc * 16 + ln];

  const size_t wbase = (size_t)ln * 256 + r16 * 8;

  #pragma unroll
  for (int kh = 0; kh < 2; kh++) {
    bf16x8 a[2][4];
    #pragma unroll
    for (int s = 0; s < 2; s++) {
      int row = m0 + s * 16 + ln;
      if (row > n - 1) row = n - 1;
      const unsigned short* zp = Z + (size_t)row * 256 + kh * 128 + r16 * 8;
      #pragma unroll
      for (int ks = 0; ks < 4; ks++) a[s][ks] = *(const bf16x8*)(zp + ks * 32);
    }
    #pragma unroll
    for (int ks = 0; ks < 4; ks++) {
      #pragma unroll
      for (int cg = 0; cg < 4; cg++) {
        bf16x8 bh[2], bl[2];
        #pragma unroll
        for (int j = 0; j < 2; j++) {
          const size_t o = wbase + (size_t)(cg * 2 + j) * 4096 + kh * 128 + ks * 32;
          bh[j] = *(const bf16x8*)(WTh + o);
          bl[j] = *(const bf16x8*)(WTl + o);
        }
        #pragma unroll
        for (int j = 0; j < 2; j++) {
          #pragma unroll
          for (int s = 0; s < 2; s++) {
            acc[s][cg * 2 + j] =
                __builtin_amdgcn_mfma_f32_16x16x32_bf16(a[s][ks], bh[j], acc[s][cg * 2 + j], 0, 0, 0);
            acc[s][cg * 2 + j] =
                __builtin_amdgcn_mfma_f32_16x16x32_bf16(a[s][ks], bl[j], acc[s][cg * 2 + j], 0, 0, 0);
          }
        }
      }
    }
  }

  if (MODE == 0) {
    #pragma unroll
    for (int s = 0; s < 2; s++)
      #pragma unroll
      for (int r = 0; r < 4; r++) {
        int node = m0 + s * 16 + r16 * 4 + r;
        if (node < n) {
          unsigned short* op = outB + (size_t)node * 256 + 128 + ln;
          #pragma unroll
          for (int cc = 0; cc < 8; cc++) {
            float v = fmaxf(acc[s][cc][r] + bv[cc], 0.f);
            op[cc * 16] = f2bf(v);
          }
        }
      }
  } else {
    float wl[8], wr[8];
    #pragma unroll
    for (int cc = 0; cc < 8; cc++) {
      wl[cc] = w3l[cc * 16 + ln];
      wr[cc] = w3r[cc * 16 + ln];
    }
    #pragma unroll
    for (int s = 0; s < 2; s++)
      #pragma unroll
      for (int r = 0; r < 4; r++) {
        float sl = 0.f, sr = 0.f;
        #pragma unroll
        for (int cc = 0; cc < 8; cc++) {
          float v = fmaxf(acc[s][cc][r] + bv[cc], 0.f);
          sl += v * wl[cc];
          sr += v * wr[cc];
        }
        sl += __shfl_xor(sl, 1); sl += __shfl_xor(sl, 2);
        sl += __shfl_xor(sl, 4); sl += __shfl_xor(sl, 8);
        sr += __shfl_xor(sr, 1); sr += __shfl_xor(sr, 2);
        sr += __shfl_xor(sr, 4); sr += __shfl_xor(sr, 8);
        int node = m0 + s * 16 + r16 * 4 + r;
        if (ln == 0 && node < n) {
          s2[node] = sl;
          r2[node] = sr;
        }
      }
  }
}

// ---------------- final scalar aggregation (16 lanes/node) ----------------
__global__ __launch_bounds__(256) void k_out3(const float* __restrict__ s2,
                                              const float* __restrict__ r2,
                                              const int* __restrict__ beg,
                                              const int* __restrict__ deg,
                                              const int* __restrict__ csr,
                                              const float* __restrict__ b3,
                                              float* __restrict__ out, int n) {
  int t = blockIdx.x * blockDim.x + threadIdx.x;
  int node = t >> 4;
  int ln = t & 15;
  if (node >= n) return;
  int bg = beg[node], d = deg[node];
  float s = 0.f;
  for (int i = ln; i < d; i += 16) s += s2[csr[bg + i]];
  s += __shfl_xor(s, 1); s += __shfl_xor(s, 2);
  s += __shfl_xor(s, 4); s += __shfl_xor(s, 8);
  if (ln == 0) out[node] = s / (d > 0 ? (float)d : 1.0f) + r2[node] + b3[0];
}

extern "C" void kernel_launch(void* const* d_in, const int* in_sizes, int n_in,
                              void* d_out, int out_size, void* d_ws, size_t ws_size,
                              hipStream_t stream) {
  const float* x   = (const float*)d_in[0];
  const int*   ei  = (const int*)d_in[1];
  const float* W1l = (const float*)d_in[2];
  const float* W1r = (const float*)d_in[3];
  const float* b1  = (const float*)d_in[4];
  const float* W2l = (const float*)d_in[5];
  const float* W2r = (const float*)d_in[6];
  const float* b2  = (const float*)d_in[7];
  const float* W3l = (const float*)d_in[8];
  const float* W3r = (const float*)d_in[9];
  const float* b3  = (const float*)d_in[10];
  float* out = (float*)d_out;

  const int N = NN;
  const int E = in_sizes[1] / 2;
  const int* src = ei;
  const int* dst = ei + E;

  char* ws = (char*)d_ws;
  size_t off = 0;
  auto alloc = [&](size_t bytes) -> char* {
    char* p = ws + off;
    off = (off + bytes + 255) & ~(size_t)255;
    return p;
  };
  int* cursor = (int*)alloc((NB + 1) * 4);
  unsigned* pairs = (unsigned*)alloc((size_t)NB * SLAB * 4);
  int* csr  = (int*)alloc(((size_t)NB * SLAB + 128) * 4);
  int* beg  = (int*)alloc((size_t)N * 4);
  int* deg  = (int*)alloc((size_t)N * 4);
  float* s2 = (float*)alloc((size_t)N * 4);
  float* r2 = (float*)alloc((size_t)N * 4);
  unsigned short* wt1h = (unsigned short*)alloc(128 * 256 * 2);
  unsigned short* wt1l = (unsigned short*)alloc(128 * 256 * 2);
  unsigned short* wt2h = (unsigned short*)alloc(128 * 256 * 2);
  unsigned short* wt2l = (unsigned short*)alloc(128 * 256 * 2);
  unsigned short* Z1 = (unsigned short*)alloc((size_t)(N + 1) * 256 * 2);
  unsigned short* Z2 = (unsigned short*)alloc((size_t)(N + 1) * 256 * 2);

  hipMemsetAsync(cursor, 0, (NB + 1) * 4, stream);

  // ---- fused prep: edge scatter | x->bf16 | weight split | zero rows ----
  const int SB = (E + 2047) / 2048;         // 782 scatter blocks
  const int XB = N * 16 / 256;              // 6250 cvt_x blocks
  k_prep<<<SB + XB + 64 + 1, 256, 0, stream>>>(
      src, dst, E, SB, cursor, pairs, x, Z1, Z2,
      W1l, W1r, W2l, W2r, wt1h, wt1l, wt2h, wt2l);
  k_build<<<NB, 256, 0, stream>>>(pairs, cursor, beg, deg, csr, N);

  const int wb = (N * 64 + 255) / 256;
  const int sb = (N + 127) / 128;           // 782 blocks (32 rows/wave)
  // ---- layer 1 ----
  k_aggZ<<<wb, 256, 0, stream>>>(Z1, beg, deg, csr, N);
  k_sage2<0><<<sb, 256, 0, stream>>>(Z1, wt1h, wt1l, b1, Z2,
                                     nullptr, nullptr, nullptr, nullptr, N);
  // ---- layer 2 (+ fused layer-3 transform) ----
  k_aggZ<<<wb, 256, 0, stream>>>(Z2, beg, deg, csr, N);
  k_sage2<1><<<sb, 256, 0, stream>>>(Z2, wt2h, wt2l, b2, nullptr,
                                     W3l, W3r, s2, r2, N);
  // ---- layer 3 scalar aggregation ----
  k_out3<<<(N * 16 + 255) / 256, 256, 0, stream>>>(s2, r2, beg, deg, csr, b3, out, N);
}

// Round 8
// 256.532 us; speedup vs baseline: 1.2610x; 1.2610x over previous
//
#include <hip/hip_runtime.h>

// 3-layer GraphSAGE, N=100000, F=H=128, E=1.6M.
// bf16 features, weights hi/lo split -> 2-term MFMA, Z=[agg|root] layout.
// One-pass slab CSR build; fused prep kernel; zero-row padded gather.
// THIS VERSION: weights stored in MFMA-FRAGMENT ORDER ([frag][lane][16B]
// 1KB blocks, frag=cidx*8+kh*4+ks, lane=r16*16+ln). R0's weight loads had
// lane-stride 512B (64 cache lines per load instruction, ~10k serialized L1
// transactions per wave -> the GEMM's real cost, proven by R7: halving the
// tile doubled scattered-load work and slowed it 50->72us). Now every weight
// load is one coalesced 1KB transaction. k_aggZ/k_sage2 tile = exact R0.

#define NN 100000
#define NB 391          // ceil(100000/256) buckets of 256 dst nodes
#define SLAB 5120       // slab capacity per bucket (mean 4096, sigma 64)

typedef short bf16x8 __attribute__((ext_vector_type(8)));
typedef float f32x4 __attribute__((ext_vector_type(4)));

static __device__ __forceinline__ float uaf(unsigned u) { return __uint_as_float(u); }
static __device__ __forceinline__ unsigned short f2bf(float f) {
  unsigned u = __float_as_uint(f);
  u += 0x7fffu + ((u >> 16) & 1u);
  return (unsigned short)(u >> 16);
}

// ---------------- fused prep: scatter | cvt_x | cvt_w | zero rows ----------------
__global__ __launch_bounds__(256) void k_prep(
    const int* __restrict__ src, const int* __restrict__ dst, int E, int SB,
    int* __restrict__ cursor, unsigned* __restrict__ pairs,
    const float* __restrict__ x, unsigned short* __restrict__ Z1,
    unsigned short* __restrict__ Z2,
    const float* __restrict__ W1l, const float* __restrict__ W1r,
    const float* __restrict__ W2l, const float* __restrict__ W2r,
    unsigned short* __restrict__ wt1h, unsigned short* __restrict__ wt1l,
    unsigned short* __restrict__ wt2h, unsigned short* __restrict__ wt2l) {
  __shared__ int h[NB];
  __shared__ int rb[NB];
  const int b = blockIdx.x;
  const int tid = threadIdx.x;
  const int XB = NN * 16 / 256;  // 6250 cvt_x blocks

  if (b < SB) {
    // ---- edge scatter into bucket slabs ----
    for (int i = tid; i < NB; i += 256) h[i] = 0;
    __syncthreads();
    int s[8], d[8];
    const int base = b * 2048 + tid * 8;
    #pragma unroll
    for (int i = 0; i < 8; i++) {
      int g = base + i;
      bool ok = g < E;
      s[i] = ok ? src[g] : 0;
      d[i] = ok ? dst[g] : -1;
      if (ok) atomicAdd(&h[d[i] >> 8], 1);
    }
    __syncthreads();
    for (int i = tid; i < NB; i += 256) {
      rb[i] = h[i] ? atomicAdd(&cursor[i], h[i]) : 0;
      h[i] = 0;
    }
    __syncthreads();
    #pragma unroll
    for (int i = 0; i < 8; i++) {
      if (d[i] >= 0) {
        int bk = d[i] >> 8;
        int off = rb[bk] + atomicAdd(&h[bk], 1);
        if (off < SLAB)
          pairs[(size_t)bk * SLAB + off] =
              ((unsigned)(d[i] & 255) << 17) | (unsigned)s[i];
      }
    }
  } else if (b < SB + XB) {
    // ---- x fp32 -> bf16 into Z1 root half ----
    int t = (b - SB) * 256 + tid;      // t < N*16
    int node = t >> 4, c = t & 15;
    const float4* xp = (const float4*)(x + (size_t)node * 128 + c * 8);
    float4 a = xp[0], bb = xp[1];
    float v[8] = {a.x, a.y, a.z, a.w, bb.x, bb.y, bb.z, bb.w};
    unsigned hh[8];
    #pragma unroll
    for (int i = 0; i < 8; i++) hh[i] = f2bf(v[i]);
    uint4 p;
    p.x = hh[0] | (hh[1] << 16); p.y = hh[2] | (hh[3] << 16);
    p.z = hh[4] | (hh[5] << 16); p.w = hh[6] | (hh[7] << 16);
    *(uint4*)(Z1 + (size_t)node * 256 + 128 + c * 8) = p;
  } else if (b < SB + XB + 64) {
    // ---- weight transpose + hi/lo split, MFMA-fragment layout ----
    // value = W[k][nn] (Wl for k<128, Wr for k>=128), stored at
    //   frag = (nn>>4)*8 + (k>>7)*4 + ((k>>5)&3)       (cidx, kh, ks)
    //   lane = ((k>>3)&3)*16 + (nn&15)                 (r16, ln)
    //   addr = frag*512 + lane*8 + (k&7)   [elements]
    // -> k_sage2's per-(kh,ks,cidx) 16B fragment loads are lane-consecutive.
    #pragma unroll
    for (int it = 0; it < 4; it++) {
      int t = (b - SB - XB) * 1024 + it * 256 + tid;  // t < 65536
      int layer = t >> 15;
      int rem = t & 32767;
      int k = rem >> 7;
      int nn = rem & 127;
      const float* Wl = layer ? W2l : W1l;
      const float* Wr = layer ? W2r : W1r;
      float v = (k < 128) ? Wl[k * 128 + nn] : Wr[(k - 128) * 128 + nn];
      unsigned short hv = f2bf(v);
      unsigned short lv = f2bf(v - uaf(((unsigned)hv) << 16));
      const int frag = (nn >> 4) * 8 + (k >> 7) * 4 + ((k >> 5) & 3);
      const int lane = ((k >> 3) & 3) * 16 + (nn & 15);
      const int addr = frag * 512 + lane * 8 + (k & 7);
      (layer ? wt2h : wt1h)[addr] = hv;
      (layer ? wt2l : wt1l)[addr] = lv;
    }
  } else {
    // ---- zero row N of Z1/Z2 (padding row for gather) ----
    unsigned* z1r = (unsigned*)(Z1 + (size_t)NN * 256);
    unsigned* z2r = (unsigned*)(Z2 + (size_t)NN * 256);
    if (tid < 128) z1r[tid] = 0;
    else z2r[tid - 128] = 0;
  }
}

// ---------------- per-bucket CSR build ----------------
__global__ __launch_bounds__(256) void k_build(const unsigned* __restrict__ pairs,
                                               const int* __restrict__ cursor,
                                               int* __restrict__ beg, int* __restrict__ deg,
                                               int* __restrict__ csr, int N) {
  __shared__ int cnt[256];
  __shared__ int sd[256];
  __shared__ int cur[256];
  const int b = blockIdx.x;
  const int tid = threadIdx.x;
  const size_t p0 = (size_t)b * SLAB;
  int count = cursor[b];
  if (count > SLAB) count = SLAB;
  cnt[tid] = 0;
  cur[tid] = 0;
  __syncthreads();
  for (int i = tid; i < count; i += 256) atomicAdd(&cnt[pairs[p0 + i] >> 17], 1);
  __syncthreads();
  int v = cnt[tid];
  sd[tid] = v;
  __syncthreads();
  #pragma unroll
  for (int off = 1; off < 256; off <<= 1) {
    int u = (tid >= off) ? sd[tid - off] : 0;
    __syncthreads();
    sd[tid] += u;
    __syncthreads();
  }
  const int node = b * 256 + tid;
  if (node < N) {
    beg[node] = (int)p0 + (sd[tid] - v);
    deg[node] = v;
  }
  __syncthreads();
  for (int i = tid; i < count; i += 256) {
    unsigned pv = pairs[p0 + i];
    int dl = pv >> 17;
    int pos = (sd[dl] - cnt[dl]) + atomicAdd(&cur[dl], 1);
    csr[p0 + pos] = pv & 0x1ffff;
  }
}

// accumulate 8 bf16 (packed in uint4) into float acc[8] -- bit-exact unpack order
#define ACC8(v)                                   \
  acc[0] += uaf((v).x << 16);                     \
  acc[1] += uaf((v).x & 0xffff0000u);             \
  acc[2] += uaf((v).y << 16);                     \
  acc[3] += uaf((v).y & 0xffff0000u);             \
  acc[4] += uaf((v).z << 16);                     \
  acc[5] += uaf((v).z & 0xffff0000u);             \
  acc[6] += uaf((v).w << 16);                     \
  acc[7] += uaf((v).w & 0xffff0000u);

// ---------------- mean aggregation over Z root halves (round-0 verified) ----------------
__global__ __launch_bounds__(256) void k_aggZ(unsigned short* __restrict__ Z,
                                              const int* __restrict__ begA,
                                              const int* __restrict__ degA,
                                              const int* __restrict__ csr, int n) {
  const int wid = (blockIdx.x * blockDim.x + threadIdx.x) >> 6;
  const int lane = threadIdx.x & 63;
  if (wid >= n) return;
  const int beg = begA[wid];
  const int d = degA[wid];
  const int g = lane >> 4, c = lane & 15;
  float acc[8] = {0.f, 0.f, 0.f, 0.f, 0.f, 0.f, 0.f, 0.f};

  for (int base = 0; base < d; base += 64) {
    int m = d - base;
    if (m > 64) m = 64;
    int idx = csr[beg + base + (lane < m ? lane : 0)];
    for (int k = 0; k < m; k += 32) {
      uint4 vA[4], vB[4];
      const bool hasB = (k + 16) < m;
      #pragma unroll
      for (int u = 0; u < 4; u++) {
        int kk = k + u * 4 + g;
        int j = __shfl(idx, kk & 63);
        j = (kk < m) ? j : NN;  // zero row
        vA[u] = *(const uint4*)(Z + (size_t)j * 256 + 128 + c * 8);
      }
      if (hasB) {
        #pragma unroll
        for (int u = 0; u < 4; u++) {
          int kk = k + 16 + u * 4 + g;
          int j = __shfl(idx, kk & 63);
          j = (kk < m) ? j : NN;
          vB[u] = *(const uint4*)(Z + (size_t)j * 256 + 128 + c * 8);
        }
      }
      #pragma unroll
      for (int u = 0; u < 4; u++) { ACC8(vA[u]); }
      if (hasB) {
        #pragma unroll
        for (int u = 0; u < 4; u++) { ACC8(vB[u]); }
      }
    }
  }
  #pragma unroll
  for (int j = 0; j < 8; j++) {
    acc[j] += __shfl_xor(acc[j], 16);
    acc[j] += __shfl_xor(acc[j], 32);
  }
  const float inv = d > 0 ? 1.0f / (float)d : 0.f;
  if (g == 0) {
    unsigned h[8];
    #pragma unroll
    for (int j = 0; j < 8; j++) h[j] = f2bf(acc[j] * inv);
    uint4 p;
    p.x = h[0] | (h[1] << 16); p.y = h[2] | (h[3] << 16);
    p.z = h[4] | (h[5] << 16); p.w = h[6] | (h[7] << 16);
    *(uint4*)(Z + (size_t)wid * 256 + c * 8) = p;
  }
}

// ---------------- streaming MFMA SAGE layer (R0 tile, fragment-order weights) ----------------
// MODE 0: out = relu(Z@W + b) bf16 -> outB[node*256 + 128 + f] (Z2 root half)
// MODE 1: h = relu(Z@W + b) fp32 regs; s2 = h.w3l, r2 = h.w3r (fused layer 3)
template <int MODE>
__global__ __launch_bounds__(256, 2) void k_sage2(
    const unsigned short* __restrict__ Z, const unsigned short* __restrict__ WTh,
    const unsigned short* __restrict__ WTl, const float* __restrict__ bias,
    unsigned short* __restrict__ outB,
    const float* __restrict__ w3l, const float* __restrict__ w3r,
    float* __restrict__ s2, float* __restrict__ r2, int n) {
  const int tid = threadIdx.x;
  const int lane = tid & 63;
  const int w = tid >> 6;
  const int ln = lane & 15;
  const int r16 = lane >> 4;
  const int m0 = blockIdx.x * 256 + w * 64;

  f32x4 acc[4][8];
  #pragma unroll
  for (int s = 0; s < 4; s++)
    #pragma unroll
    for (int cc = 0; cc < 8; cc++) {
      acc[s][cc][0] = 0.f; acc[s][cc][1] = 0.f;
      acc[s][cc][2] = 0.f; acc[s][cc][3] = 0.f;
    }
  float bv[8];
  #pragma unroll
  for (int cc = 0; cc < 8; cc++) bv[cc] = bias[cc * 16 + ln];

  #pragma unroll
  for (int kh = 0; kh < 2; kh++) {
    bf16x8 a[4][4];
    #pragma unroll
    for (int s = 0; s < 4; s++) {
      int row = m0 + s * 16 + ln;
      if (row > n - 1) row = n - 1;
      const unsigned short* zp = Z + (size_t)row * 256 + kh * 128 + r16 * 8;
      #pragma unroll
      for (int ks = 0; ks < 4; ks++) a[s][ks] = *(const bf16x8*)(zp + ks * 32);
    }
    #pragma unroll
    for (int ks = 0; ks < 4; ks++) {
      #pragma unroll
      for (int cg = 0; cg < 4; cg++) {
        bf16x8 bh[2], bl[2];
        #pragma unroll
        for (int j = 0; j < 2; j++) {
          // fragment-order: frag = cidx*8 + kh*4 + ks, 512 elem/frag, lane*8
          const size_t o = (size_t)(((cg * 2 + j) * 8 + kh * 4 + ks) * 512 + lane * 8);
          bh[j] = *(const bf16x8*)(WTh + o);
          bl[j] = *(const bf16x8*)(WTl + o);
        }
        #pragma unroll
        for (int j = 0; j < 2; j++) {
          #pragma unroll
          for (int s = 0; s < 4; s++) {
            acc[s][cg * 2 + j] =
                __builtin_amdgcn_mfma_f32_16x16x32_bf16(a[s][ks], bh[j], acc[s][cg * 2 + j], 0, 0, 0);
            acc[s][cg * 2 + j] =
                __builtin_amdgcn_mfma_f32_16x16x32_bf16(a[s][ks], bl[j], acc[s][cg * 2 + j], 0, 0, 0);
          }
        }
      }
    }
  }

  if (MODE == 0) {
    #pragma unroll
    for (int s = 0; s < 4; s++)
      #pragma unroll
      for (int r = 0; r < 4; r++) {
        int node = m0 + s * 16 + r16 * 4 + r;
        if (node < n) {
          unsigned short* op = outB + (size_t)node * 256 + 128 + ln;
          #pragma unroll
          for (int cc = 0; cc < 8; cc++) {
            float v = fmaxf(acc[s][cc][r] + bv[cc], 0.f);
            op[cc * 16] = f2bf(v);
          }
        }
      }
  } else {
    float wl[8], wr[8];
    #pragma unroll
    for (int cc = 0; cc < 8; cc++) {
      wl[cc] = w3l[cc * 16 + ln];
      wr[cc] = w3r[cc * 16 + ln];
    }
    #pragma unroll
    for (int s = 0; s < 4; s++)
      #pragma unroll
      for (int r = 0; r < 4; r++) {
        float sl = 0.f, sr = 0.f;
        #pragma unroll
        for (int cc = 0; cc < 8; cc++) {
          float v = fmaxf(acc[s][cc][r] + bv[cc], 0.f);
          sl += v * wl[cc];
          sr += v * wr[cc];
        }
        sl += __shfl_xor(sl, 1); sl += __shfl_xor(sl, 2);
        sl += __shfl_xor(sl, 4); sl += __shfl_xor(sl, 8);
        sr += __shfl_xor(sr, 1); sr += __shfl_xor(sr, 2);
        sr += __shfl_xor(sr, 4); sr += __shfl_xor(sr, 8);
        int node = m0 + s * 16 + r16 * 4 + r;
        if (ln == 0 && node < n) {
          s2[node] = sl;
          r2[node] = sr;
        }
      }
  }
}

// ---------------- final scalar aggregation (16 lanes/node) ----------------
__global__ __launch_bounds__(256) void k_out3(const float* __restrict__ s2,
                                              const float* __restrict__ r2,
                                              const int* __restrict__ beg,
                                              const int* __restrict__ deg,
                                              const int* __restrict__ csr,
                                              const float* __restrict__ b3,
                                              float* __restrict__ out, int n) {
  int t = blockIdx.x * blockDim.x + threadIdx.x;
  int node = t >> 4;
  int ln = t & 15;
  if (node >= n) return;
  int bg = beg[node], d = deg[node];
  float s = 0.f;
  for (int i = ln; i < d; i += 16) s += s2[csr[bg + i]];
  s += __shfl_xor(s, 1); s += __shfl_xor(s, 2);
  s += __shfl_xor(s, 4); s += __shfl_xor(s, 8);
  if (ln == 0) out[node] = s / (d > 0 ? (float)d : 1.0f) + r2[node] + b3[0];
}

extern "C" void kernel_launch(void* const* d_in, const int* in_sizes, int n_in,
                              void* d_out, int out_size, void* d_ws, size_t ws_size,
                              hipStream_t stream) {
  const float* x   = (const float*)d_in[0];
  const int*   ei  = (const int*)d_in[1];
  const float* W1l = (const float*)d_in[2];
  const float* W1r = (const float*)d_in[3];
  const float* b1  = (const float*)d_in[4];
  const float* W2l = (const float*)d_in[5];
  const float* W2r = (const float*)d_in[6];
  const float* b2  = (const float*)d_in[7];
  const float* W3l = (const float*)d_in[8];
  const float* W3r = (const float*)d_in[9];
  const float* b3  = (const float*)d_in[10];
  float* out = (float*)d_out;

  const int N = NN;
  const int E = in_sizes[1] / 2;
  const int* src = ei;
  const int* dst = ei + E;

  char* ws = (char*)d_ws;
  size_t off = 0;
  auto alloc = [&](size_t bytes) -> char* {
    char* p = ws + off;
    off = (off + bytes + 255) & ~(size_t)255;
    return p;
  };
  int* cursor = (int*)alloc((NB + 1) * 4);
  unsigned* pairs = (unsigned*)alloc((size_t)NB * SLAB * 4);
  int* csr  = (int*)alloc(((size_t)NB * SLAB + 128) * 4);
  int* beg  = (int*)alloc((size_t)N * 4);
  int* deg  = (int*)alloc((size_t)N * 4);
  float* s2 = (float*)alloc((size_t)N * 4);
  float* r2 = (float*)alloc((size_t)N * 4);
  unsigned short* wt1h = (unsigned short*)alloc(128 * 256 * 2);
  unsigned short* wt1l = (unsigned short*)alloc(128 * 256 * 2);
  unsigned short* wt2h = (unsigned short*)alloc(128 * 256 * 2);
  unsigned short* wt2l = (unsigned short*)alloc(128 * 256 * 2);
  unsigned short* Z1 = (unsigned short*)alloc((size_t)(N + 1) * 256 * 2);
  unsigned short* Z2 = (unsigned short*)alloc((size_t)(N + 1) * 256 * 2);

  hipMemsetAsync(cursor, 0, (NB + 1) * 4, stream);

  // ---- fused prep: edge scatter | x->bf16 | weight split | zero rows ----
  const int SB = (E + 2047) / 2048;         // 782 scatter blocks
  const int XB = N * 16 / 256;              // 6250 cvt_x blocks
  k_prep<<<SB + XB + 64 + 1, 256, 0, stream>>>(
      src, dst, E, SB, cursor, pairs, x, Z1, Z2,
      W1l, W1r, W2l, W2r, wt1h, wt1l, wt2h, wt2l);
  k_build<<<NB, 256, 0, stream>>>(pairs, cursor, beg, deg, csr, N);

  const int wb = (N * 64 + 255) / 256;
  const int sb = (N + 255) / 256;
  // ---- layer 1 ----
  k_aggZ<<<wb, 256, 0, stream>>>(Z1, beg, deg, csr, N);
  k_sage2<0><<<sb, 256, 0, stream>>>(Z1, wt1h, wt1l, b1, Z2,
                                     nullptr, nullptr, nullptr, nullptr, N);
  // ---- layer 2 (+ fused layer-3 transform) ----
  k_aggZ<<<wb, 256, 0, stream>>>(Z2, beg, deg, csr, N);
  k_sage2<1><<<sb, 256, 0, stream>>>(Z2, wt2h, wt2l, b2, nullptr,
                                     W3l, W3r, s2, r2, N);
  // ---- layer 3 scalar aggregation ----
  k_out3<<<(N * 16 + 255) / 256, 256, 0, stream>>>(s2, r2, beg, deg, csr, b3, out, N);
}

// Round 9
// 248.650 us; speedup vs baseline: 1.3010x; 1.0317x over previous
//
#include <hip/hip_runtime.h>

// 3-layer GraphSAGE, N=100000, F=H=128, E=1.6M.
// bf16 features, weights hi/lo split -> 2-term MFMA, Z=[agg|root] layout.
// One-pass slab CSR build; fused prep kernel; zero-row padded gather.
// THIS VERSION (on top of R8's fragment-order weights): k_sage2 SWAPS the
// MFMA operands (acc = mfma(W_frag, Z_frag, acc)). A/B fragment layouts are
// symmetric on gfx950, so the same arrays feed both roles; the output tile
// comes out transposed: lane holds 4 CONSECUTIVE features of one node
// (row=feat=(lane>>4)*4+reg, col=node=lane&15). The C-store becomes 32x8B
// semi-coalesced stores (512 lines/wave) instead of 128 scalar ushort
// scatters (8192 lines/wave) -- the same L1-transaction pathology R8 fixed
// for the weight loads, now fixed for the stores. Values bit-identical.

#define NN 100000
#define NB 391          // ceil(100000/256) buckets of 256 dst nodes
#define SLAB 5120       // slab capacity per bucket (mean 4096, sigma 64)

typedef short bf16x8 __attribute__((ext_vector_type(8)));
typedef float f32x4 __attribute__((ext_vector_type(4)));

static __device__ __forceinline__ float uaf(unsigned u) { return __uint_as_float(u); }
static __device__ __forceinline__ unsigned short f2bf(float f) {
  unsigned u = __float_as_uint(f);
  u += 0x7fffu + ((u >> 16) & 1u);
  return (unsigned short)(u >> 16);
}

// ---------------- fused prep: scatter | cvt_x | cvt_w | zero rows ----------------
__global__ __launch_bounds__(256) void k_prep(
    const int* __restrict__ src, const int* __restrict__ dst, int E, int SB,
    int* __restrict__ cursor, unsigned* __restrict__ pairs,
    const float* __restrict__ x, unsigned short* __restrict__ Z1,
    unsigned short* __restrict__ Z2,
    const float* __restrict__ W1l, const float* __restrict__ W1r,
    const float* __restrict__ W2l, const float* __restrict__ W2r,
    unsigned short* __restrict__ wt1h, unsigned short* __restrict__ wt1l,
    unsigned short* __restrict__ wt2h, unsigned short* __restrict__ wt2l) {
  __shared__ int h[NB];
  __shared__ int rb[NB];
  const int b = blockIdx.x;
  const int tid = threadIdx.x;
  const int XB = NN * 16 / 256;  // 6250 cvt_x blocks

  if (b < SB) {
    // ---- edge scatter into bucket slabs ----
    for (int i = tid; i < NB; i += 256) h[i] = 0;
    __syncthreads();
    int s[8], d[8];
    const int base = b * 2048 + tid * 8;
    #pragma unroll
    for (int i = 0; i < 8; i++) {
      int g = base + i;
      bool ok = g < E;
      s[i] = ok ? src[g] : 0;
      d[i] = ok ? dst[g] : -1;
      if (ok) atomicAdd(&h[d[i] >> 8], 1);
    }
    __syncthreads();
    for (int i = tid; i < NB; i += 256) {
      rb[i] = h[i] ? atomicAdd(&cursor[i], h[i]) : 0;
      h[i] = 0;
    }
    __syncthreads();
    #pragma unroll
    for (int i = 0; i < 8; i++) {
      if (d[i] >= 0) {
        int bk = d[i] >> 8;
        int off = rb[bk] + atomicAdd(&h[bk], 1);
        if (off < SLAB)
          pairs[(size_t)bk * SLAB + off] =
              ((unsigned)(d[i] & 255) << 17) | (unsigned)s[i];
      }
    }
  } else if (b < SB + XB) {
    // ---- x fp32 -> bf16 into Z1 root half ----
    int t = (b - SB) * 256 + tid;      // t < N*16
    int node = t >> 4, c = t & 15;
    const float4* xp = (const float4*)(x + (size_t)node * 128 + c * 8);
    float4 a = xp[0], bb = xp[1];
    float v[8] = {a.x, a.y, a.z, a.w, bb.x, bb.y, bb.z, bb.w};
    unsigned hh[8];
    #pragma unroll
    for (int i = 0; i < 8; i++) hh[i] = f2bf(v[i]);
    uint4 p;
    p.x = hh[0] | (hh[1] << 16); p.y = hh[2] | (hh[3] << 16);
    p.z = hh[4] | (hh[5] << 16); p.w = hh[6] | (hh[7] << 16);
    *(uint4*)(Z1 + (size_t)node * 256 + 128 + c * 8) = p;
  } else if (b < SB + XB + 64) {
    // ---- weight transpose + hi/lo split, MFMA-fragment layout ----
    // value = W[k][nn] (Wl for k<128, Wr for k>=128), stored at
    //   frag = (nn>>4)*8 + (k>>7)*4 + ((k>>5)&3)       (cidx, kh, ks)
    //   lane = ((k>>3)&3)*16 + (nn&15)                 (r16, ln)
    //   addr = frag*512 + lane*8 + (k&7)   [elements]
    #pragma unroll
    for (int it = 0; it < 4; it++) {
      int t = (b - SB - XB) * 1024 + it * 256 + tid;  // t < 65536
      int layer = t >> 15;
      int rem = t & 32767;
      int k = rem >> 7;
      int nn = rem & 127;
      const float* Wl = layer ? W2l : W1l;
      const float* Wr = layer ? W2r : W1r;
      float v = (k < 128) ? Wl[k * 128 + nn] : Wr[(k - 128) * 128 + nn];
      unsigned short hv = f2bf(v);
      unsigned short lv = f2bf(v - uaf(((unsigned)hv) << 16));
      const int frag = (nn >> 4) * 8 + (k >> 7) * 4 + ((k >> 5) & 3);
      const int lane = ((k >> 3) & 3) * 16 + (nn & 15);
      const int addr = frag * 512 + lane * 8 + (k & 7);
      (layer ? wt2h : wt1h)[addr] = hv;
      (layer ? wt2l : wt1l)[addr] = lv;
    }
  } else {
    // ---- zero row N of Z1/Z2 (padding row for gather) ----
    unsigned* z1r = (unsigned*)(Z1 + (size_t)NN * 256);
    unsigned* z2r = (unsigned*)(Z2 + (size_t)NN * 256);
    if (tid < 128) z1r[tid] = 0;
    else z2r[tid - 128] = 0;
  }
}

// ---------------- per-bucket CSR build ----------------
__global__ __launch_bounds__(256) void k_build(const unsigned* __restrict__ pairs,
                                               const int* __restrict__ cursor,
                                               int* __restrict__ beg, int* __restrict__ deg,
                                               int* __restrict__ csr, int N) {
  __shared__ int cnt[256];
  __shared__ int sd[256];
  __shared__ int cur[256];
  const int b = blockIdx.x;
  const int tid = threadIdx.x;
  const size_t p0 = (size_t)b * SLAB;
  int count = cursor[b];
  if (count > SLAB) count = SLAB;
  cnt[tid] = 0;
  cur[tid] = 0;
  __syncthreads();
  for (int i = tid; i < count; i += 256) atomicAdd(&cnt[pairs[p0 + i] >> 17], 1);
  __syncthreads();
  int v = cnt[tid];
  sd[tid] = v;
  __syncthreads();
  #pragma unroll
  for (int off = 1; off < 256; off <<= 1) {
    int u = (tid >= off) ? sd[tid - off] : 0;
    __syncthreads();
    sd[tid] += u;
    __syncthreads();
  }
  const int node = b * 256 + tid;
  if (node < N) {
    beg[node] = (int)p0 + (sd[tid] - v);
    deg[node] = v;
  }
  __syncthreads();
  for (int i = tid; i < count; i += 256) {
    unsigned pv = pairs[p0 + i];
    int dl = pv >> 17;
    int pos = (sd[dl] - cnt[dl]) + atomicAdd(&cur[dl], 1);
    csr[p0 + pos] = pv & 0x1ffff;
  }
}

// accumulate 8 bf16 (packed in uint4) into float acc[8] -- bit-exact unpack order
#define ACC8(v)                                   \
  acc[0] += uaf((v).x << 16);                     \
  acc[1] += uaf((v).x & 0xffff0000u);             \
  acc[2] += uaf((v).y << 16);                     \
  acc[3] += uaf((v).y & 0xffff0000u);             \
  acc[4] += uaf((v).z << 16);                     \
  acc[5] += uaf((v).z & 0xffff0000u);             \
  acc[6] += uaf((v).w << 16);                     \
  acc[7] += uaf((v).w & 0xffff0000u);

// ---------------- mean aggregation over Z root halves (round-0 verified) ----------------
__global__ __launch_bounds__(256) void k_aggZ(unsigned short* __restrict__ Z,
                                              const int* __restrict__ begA,
                                              const int* __restrict__ degA,
                                              const int* __restrict__ csr, int n) {
  const int wid = (blockIdx.x * blockDim.x + threadIdx.x) >> 6;
  const int lane = threadIdx.x & 63;
  if (wid >= n) return;
  const int beg = begA[wid];
  const int d = degA[wid];
  const int g = lane >> 4, c = lane & 15;
  float acc[8] = {0.f, 0.f, 0.f, 0.f, 0.f, 0.f, 0.f, 0.f};

  for (int base = 0; base < d; base += 64) {
    int m = d - base;
    if (m > 64) m = 64;
    int idx = csr[beg + base + (lane < m ? lane : 0)];
    for (int k = 0; k < m; k += 32) {
      uint4 vA[4], vB[4];
      const bool hasB = (k + 16) < m;
      #pragma unroll
      for (int u = 0; u < 4; u++) {
        int kk = k + u * 4 + g;
        int j = __shfl(idx, kk & 63);
        j = (kk < m) ? j : NN;  // zero row
        vA[u] = *(const uint4*)(Z + (size_t)j * 256 + 128 + c * 8);
      }
      if (hasB) {
        #pragma unroll
        for (int u = 0; u < 4; u++) {
          int kk = k + 16 + u * 4 + g;
          int j = __shfl(idx, kk & 63);
          j = (kk < m) ? j : NN;
          vB[u] = *(const uint4*)(Z + (size_t)j * 256 + 128 + c * 8);
        }
      }
      #pragma unroll
      for (int u = 0; u < 4; u++) { ACC8(vA[u]); }
      if (hasB) {
        #pragma unroll
        for (int u = 0; u < 4; u++) { ACC8(vB[u]); }
      }
    }
  }
  #pragma unroll
  for (int j = 0; j < 8; j++) {
    acc[j] += __shfl_xor(acc[j], 16);
    acc[j] += __shfl_xor(acc[j], 32);
  }
  const float inv = d > 0 ? 1.0f / (float)d : 0.f;
  if (g == 0) {
    unsigned h[8];
    #pragma unroll
    for (int j = 0; j < 8; j++) h[j] = f2bf(acc[j] * inv);
    uint4 p;
    p.x = h[0] | (h[1] << 16); p.y = h[2] | (h[3] << 16);
    p.z = h[4] | (h[5] << 16); p.w = h[6] | (h[7] << 16);
    *(uint4*)(Z + (size_t)wid * 256 + c * 8) = p;
  }
}

// ---------------- streaming MFMA SAGE layer (swapped operands, coalesced C) ----------------
// acc[s][cc] = mfma(W_frag, Z_frag, acc): lane holds feature = cc*16+r16*4+r,
// node = m0+s*16+ln. Same products, same k order as before -> identical values,
// transposed placement -> 8B-contiguous per-lane stores.
// MODE 0: out = relu(Z@W + b) bf16 -> outB[node*256 + 128 + f] (Z2 root half)
// MODE 1: h = relu(Z@W + b); s2 = h.w3l, r2 = h.w3r (fused layer 3)
template <int MODE>
__global__ __launch_bounds__(256, 2) void k_sage2(
    const unsigned short* __restrict__ Z, const unsigned short* __restrict__ WTh,
    const unsigned short* __restrict__ WTl, const float* __restrict__ bias,
    unsigned short* __restrict__ outB,
    const float* __restrict__ w3l, const float* __restrict__ w3r,
    float* __restrict__ s2, float* __restrict__ r2, int n) {
  const int tid = threadIdx.x;
  const int lane = tid & 63;
  const int w = tid >> 6;
  const int ln = lane & 15;
  const int r16 = lane >> 4;
  const int m0 = blockIdx.x * 256 + w * 64;

  f32x4 acc[4][8];
  #pragma unroll
  for (int s = 0; s < 4; s++)
    #pragma unroll
    for (int cc = 0; cc < 8; cc++) {
      acc[s][cc][0] = 0.f; acc[s][cc][1] = 0.f;
      acc[s][cc][2] = 0.f; acc[s][cc][3] = 0.f;
    }
  // bias fragment: feature = cc*16 + r16*4 + r
  float4 bv4[8];
  #pragma unroll
  for (int cc = 0; cc < 8; cc++) bv4[cc] = *(const float4*)(bias + cc * 16 + r16 * 4);

  #pragma unroll
  for (int kh = 0; kh < 2; kh++) {
    bf16x8 a[4][4];
    #pragma unroll
    for (int s = 0; s < 4; s++) {
      int row = m0 + s * 16 + ln;
      if (row > n - 1) row = n - 1;
      const unsigned short* zp = Z + (size_t)row * 256 + kh * 128 + r16 * 8;
      #pragma unroll
      for (int ks = 0; ks < 4; ks++) a[s][ks] = *(const bf16x8*)(zp + ks * 32);
    }
    #pragma unroll
    for (int ks = 0; ks < 4; ks++) {
      #pragma unroll
      for (int cg = 0; cg < 4; cg++) {
        bf16x8 bh[2], bl[2];
        #pragma unroll
        for (int j = 0; j < 2; j++) {
          // fragment-order: frag = cidx*8 + kh*4 + ks, 512 elem/frag, lane*8
          const size_t o = (size_t)(((cg * 2 + j) * 8 + kh * 4 + ks) * 512 + lane * 8);
          bh[j] = *(const bf16x8*)(WTh + o);
          bl[j] = *(const bf16x8*)(WTl + o);
        }
        #pragma unroll
        for (int j = 0; j < 2; j++) {
          #pragma unroll
          for (int s = 0; s < 4; s++) {
            acc[s][cg * 2 + j] =
                __builtin_amdgcn_mfma_f32_16x16x32_bf16(bh[j], a[s][ks], acc[s][cg * 2 + j], 0, 0, 0);
            acc[s][cg * 2 + j] =
                __builtin_amdgcn_mfma_f32_16x16x32_bf16(bl[j], a[s][ks], acc[s][cg * 2 + j], 0, 0, 0);
          }
        }
      }
    }
  }

  if (MODE == 0) {
    #pragma unroll
    for (int s = 0; s < 4; s++) {
      const int node = m0 + s * 16 + ln;
      if (node < n) {
        unsigned short* op = outB + (size_t)node * 256 + 128 + r16 * 4;
        #pragma unroll
        for (int cc = 0; cc < 8; cc++) {
          ushort4 hq;
          hq.x = f2bf(fmaxf(acc[s][cc][0] + bv4[cc].x, 0.f));
          hq.y = f2bf(fmaxf(acc[s][cc][1] + bv4[cc].y, 0.f));
          hq.z = f2bf(fmaxf(acc[s][cc][2] + bv4[cc].z, 0.f));
          hq.w = f2bf(fmaxf(acc[s][cc][3] + bv4[cc].w, 0.f));
          *(ushort4*)(op + cc * 16) = hq;
        }
      }
    }
  } else {
    float4 wl4[8], wr4[8];
    #pragma unroll
    for (int cc = 0; cc < 8; cc++) {
      wl4[cc] = *(const float4*)(w3l + cc * 16 + r16 * 4);
      wr4[cc] = *(const float4*)(w3r + cc * 16 + r16 * 4);
    }
    #pragma unroll
    for (int s = 0; s < 4; s++) {
      float sl = 0.f, sr = 0.f;
      #pragma unroll
      for (int cc = 0; cc < 8; cc++) {
        float v0 = fmaxf(acc[s][cc][0] + bv4[cc].x, 0.f);
        float v1 = fmaxf(acc[s][cc][1] + bv4[cc].y, 0.f);
        float v2 = fmaxf(acc[s][cc][2] + bv4[cc].z, 0.f);
        float v3 = fmaxf(acc[s][cc][3] + bv4[cc].w, 0.f);
        sl += v0 * wl4[cc].x + v1 * wl4[cc].y + v2 * wl4[cc].z + v3 * wl4[cc].w;
        sr += v0 * wr4[cc].x + v1 * wr4[cc].y + v2 * wr4[cc].z + v3 * wr4[cc].w;
      }
      sl += __shfl_xor(sl, 16); sl += __shfl_xor(sl, 32);
      sr += __shfl_xor(sr, 16); sr += __shfl_xor(sr, 32);
      const int node = m0 + s * 16 + ln;
      if (r16 == 0 && node < n) {
        s2[node] = sl;
        r2[node] = sr;
      }
    }
  }
}

// ---------------- final scalar aggregation (16 lanes/node) ----------------
__global__ __launch_bounds__(256) void k_out3(const float* __restrict__ s2,
                                              const float* __restrict__ r2,
                                              const int* __restrict__ beg,
                                              const int* __restrict__ deg,
                                              const int* __restrict__ csr,
                                              const float* __restrict__ b3,
                                              float* __restrict__ out, int n) {
  int t = blockIdx.x * blockDim.x + threadIdx.x;
  int node = t >> 4;
  int ln = t & 15;
  if (node >= n) return;
  int bg = beg[node], d = deg[node];
  float s = 0.f;
  for (int i = ln; i < d; i += 16) s += s2[csr[bg + i]];
  s += __shfl_xor(s, 1); s += __shfl_xor(s, 2);
  s += __shfl_xor(s, 4); s += __shfl_xor(s, 8);
  if (ln == 0) out[node] = s / (d > 0 ? (float)d : 1.0f) + r2[node] + b3[0];
}

extern "C" void kernel_launch(void* const* d_in, const int* in_sizes, int n_in,
                              void* d_out, int out_size, void* d_ws, size_t ws_size,
                              hipStream_t stream) {
  const float* x   = (const float*)d_in[0];
  const int*   ei  = (const int*)d_in[1];
  const float* W1l = (const float*)d_in[2];
  const float* W1r = (const float*)d_in[3];
  const float* b1  = (const float*)d_in[4];
  const float* W2l = (const float*)d_in[5];
  const float* W2r = (const float*)d_in[6];
  const float* b2  = (const float*)d_in[7];
  const float* W3l = (const float*)d_in[8];
  const float* W3r = (const float*)d_in[9];
  const float* b3  = (const float*)d_in[10];
  float* out = (float*)d_out;

  const int N = NN;
  const int E = in_sizes[1] / 2;
  const int* src = ei;
  const int* dst = ei + E;

  char* ws = (char*)d_ws;
  size_t off = 0;
  auto alloc = [&](size_t bytes) -> char* {
    char* p = ws + off;
    off = (off + bytes + 255) & ~(size_t)255;
    return p;
  };
  int* cursor = (int*)alloc((NB + 1) * 4);
  unsigned* pairs = (unsigned*)alloc((size_t)NB * SLAB * 4);
  int* csr  = (int*)alloc(((size_t)NB * SLAB + 128) * 4);
  int* beg  = (int*)alloc((size_t)N * 4);
  int* deg  = (int*)alloc((size_t)N * 4);
  float* s2 = (float*)alloc((size_t)N * 4);
  float* r2 = (float*)alloc((size_t)N * 4);
  unsigned short* wt1h = (unsigned short*)alloc(128 * 256 * 2);
  unsigned short* wt1l = (unsigned short*)alloc(128 * 256 * 2);
  unsigned short* wt2h = (unsigned short*)alloc(128 * 256 * 2);
  unsigned short* wt2l = (unsigned short*)alloc(128 * 256 * 2);
  unsigned short* Z1 = (unsigned short*)alloc((size_t)(N + 1) * 256 * 2);
  unsigned short* Z2 = (unsigned short*)alloc((size_t)(N + 1) * 256 * 2);

  hipMemsetAsync(cursor, 0, (NB + 1) * 4, stream);

  // ---- fused prep: edge scatter | x->bf16 | weight split | zero rows ----
  const int SB = (E + 2047) / 2048;         // 782 scatter blocks
  const int XB = N * 16 / 256;              // 6250 cvt_x blocks
  k_prep<<<SB + XB + 64 + 1, 256, 0, stream>>>(
      src, dst, E, SB, cursor, pairs, x, Z1, Z2,
      W1l, W1r, W2l, W2r, wt1h, wt1l, wt2h, wt2l);
  k_build<<<NB, 256, 0, stream>>>(pairs, cursor, beg, deg, csr, N);

  const int wb = (N * 64 + 255) / 256;
  const int sb = (N + 255) / 256;
  // ---- layer 1 ----
  k_aggZ<<<wb, 256, 0, stream>>>(Z1, beg, deg, csr, N);
  k_sage2<0><<<sb, 256, 0, stream>>>(Z1, wt1h, wt1l, b1, Z2,
                                     nullptr, nullptr, nullptr, nullptr, N);
  // ---- layer 2 (+ fused layer-3 transform) ----
  k_aggZ<<<wb, 256, 0, stream>>>(Z2, beg, deg, csr, N);
  k_sage2<1><<<sb, 256, 0, stream>>>(Z2, wt2h, wt2l, b2, nullptr,
                                     W3l, W3r, s2, r2, N);
  // ---- layer 3 scalar aggregation ----
  k_out3<<<(N * 16 + 255) / 256, 256, 0, stream>>>(s2, r2, beg, deg, csr, b3, out, N);
}